// Round 1
// baseline (225.193 us; speedup 1.0000x reference)
//
#include <hip/hip_runtime.h>
#include <math.h>

#define DD 64
#define LL 2048
#define TQ 128
#define TK 64
// fold 1/sqrt(64) and log2(e) into one scale; leaky_relu commutes with positive scaling
#define SCALE_LOG2 (0.125f * 1.44269504088896340736f)

typedef __bf16 bf16_t;
typedef __bf16 bf16x8 __attribute__((ext_vector_type(8)));
typedef __bf16 bf16x4 __attribute__((ext_vector_type(4)));
typedef float f32x4 __attribute__((ext_vector_type(4)));

// LDS strides: 64+8 = 72 elems = 144 B = 9*16B -> b128-aligned rows, 4-bank shift/row (2-way, free)
union __align__(16) SMem {
  struct {
    bf16_t Qs[TQ][72];   // [lq][d]   (transposed from global)
    bf16_t Ks[TK][72];   // [lk][d]   (transposed from global)
    bf16_t Vs[DD][72];   // [d][lk]   (natural)
    bf16_t Ps[TQ][72];   // [lq][lk]  (P round-trip)
  } a;
  float Oe[TQ][65];      // epilogue transpose buffer (33280 B < 55296 B)
};

__global__ __launch_bounds__(256, 2)
void attn_flash_bf16(const float* __restrict__ q, const float* __restrict__ k,
                     const float* __restrict__ v, float* __restrict__ out) {
  __shared__ SMem sm;
  const int tid  = threadIdx.x;
  const int w    = tid >> 6;        // wave 0..3
  const int lane = tid & 63;
  const int qu   = lane >> 4;       // quad 0..3
  const int c    = lane & 15;       // col-in-tile
  const int head = blockIdx.y;      // 0..31 (B*H)
  const int q0   = blockIdx.x * TQ;
  const size_t hoff = (size_t)head * DD * LL;
  const float* qp = q + hoff;
  const float* kp = k + hoff;
  const float* vp = v + hoff;

  // ---- stage Q once: Qs[lq][d] = q[d][q0+lq], fp32->bf16 ----
  for (int i = 0; i < 8; ++i) {
    int idx = tid + i * 256;              // 0..2047
    int d   = idx >> 5;                   // 0..63
    int c4  = (idx & 31) * 4;             // lq 0..124
    const float4 qv = *(const float4*)(qp + d * LL + q0 + c4);
    sm.a.Qs[c4 + 0][d] = (bf16_t)qv.x;
    sm.a.Qs[c4 + 1][d] = (bf16_t)qv.y;
    sm.a.Qs[c4 + 2][d] = (bf16_t)qv.z;
    sm.a.Qs[c4 + 3][d] = (bf16_t)qv.w;
  }

  // per-wave output strip: rows lq in [w*32, w*32+32), all 64 d cols
  f32x4 oacc[2][4];
  float m_run[2][4], l_run[2][4];
  for (int mt = 0; mt < 2; ++mt)
    for (int r = 0; r < 4; ++r) {
      m_run[mt][r] = -INFINITY;
      l_run[mt][r] = 0.f;
    }
  for (int mt = 0; mt < 2; ++mt)
    for (int nt = 0; nt < 4; ++nt)
      for (int j = 0; j < 4; ++j) oacc[mt][nt][j] = 0.f;

  const int wbase = w * 32;

  for (int t = 0; t < LL / TK; ++t) {
    const int lk0 = t * TK;
    __syncthreads();  // previous iter's PV reads of Ks/Vs done before restage
    // ---- stage K (transpose) + V (straight), fp32->bf16 ----
    for (int i = 0; i < 4; ++i) {
      int idx = tid + i * 256;            // 0..1023
      int d   = idx >> 4;                 // 0..63
      int c4  = (idx & 15) * 4;           // lk 0..60
      const float4 kv = *(const float4*)(kp + d * LL + lk0 + c4);
      sm.a.Ks[c4 + 0][d] = (bf16_t)kv.x;
      sm.a.Ks[c4 + 1][d] = (bf16_t)kv.y;
      sm.a.Ks[c4 + 2][d] = (bf16_t)kv.z;
      sm.a.Ks[c4 + 3][d] = (bf16_t)kv.w;
      const float4 vv = *(const float4*)(vp + d * LL + lk0 + c4);
      bf16x4 pk;
      pk[0] = (bf16_t)vv.x; pk[1] = (bf16_t)vv.y;
      pk[2] = (bf16_t)vv.z; pk[3] = (bf16_t)vv.w;
      *(bf16x4*)&sm.a.Vs[d][c4] = pk;
    }
    __syncthreads();

    // ---- S = Q^T K : C[m=lq][n=lk], per-wave 32x64 ----
    f32x4 sacc[2][4];
    for (int mt = 0; mt < 2; ++mt)
      for (int nt = 0; nt < 4; ++nt)
        for (int j = 0; j < 4; ++j) sacc[mt][nt][j] = 0.f;
    for (int kk = 0; kk < 2; ++kk) {
      bf16x8 aq[2];
      for (int mt = 0; mt < 2; ++mt)
        aq[mt] = *(const bf16x8*)&sm.a.Qs[wbase + mt * 16 + c][kk * 32 + qu * 8];
      for (int nt = 0; nt < 4; ++nt) {
        bf16x8 bk = *(const bf16x8*)&sm.a.Ks[nt * 16 + c][kk * 32 + qu * 8];
        for (int mt = 0; mt < 2; ++mt)
          sacc[mt][nt] = __builtin_amdgcn_mfma_f32_16x16x32_bf16(aq[mt], bk, sacc[mt][nt], 0, 0, 0);
      }
    }

    // ---- online softmax, log2 domain; leaky = max(x, 0.01x) ----
    for (int mt = 0; mt < 2; ++mt) {
      for (int r = 0; r < 4; ++r) {
        float mx = -INFINITY;
        for (int nt = 0; nt < 4; ++nt) {
          float s = sacc[mt][nt][r] * SCALE_LOG2;
          s = fmaxf(s, 0.01f * s);
          sacc[mt][nt][r] = s;
          mx = fmaxf(mx, s);
        }
        mx = fmaxf(mx, __shfl_xor(mx, 1));
        mx = fmaxf(mx, __shfl_xor(mx, 2));
        mx = fmaxf(mx, __shfl_xor(mx, 4));
        mx = fmaxf(mx, __shfl_xor(mx, 8));
        float mold = m_run[mt][r];
        float mnew = fmaxf(mold, mx);
        float alpha = __builtin_amdgcn_exp2f(mold - mnew);  // exp2(-inf)=0 first iter
        m_run[mt][r] = mnew;
        float rs = 0.f;
        const int lq = wbase + mt * 16 + qu * 4 + r;
        for (int nt = 0; nt < 4; ++nt) {
          float p = __builtin_amdgcn_exp2f(sacc[mt][nt][r] - mnew);
          rs += p;
          sm.a.Ps[lq][nt * 16 + c] = (bf16_t)p;  // wave-private rows: no barrier needed
        }
        rs += __shfl_xor(rs, 1);
        rs += __shfl_xor(rs, 2);
        rs += __shfl_xor(rs, 4);
        rs += __shfl_xor(rs, 8);
        l_run[mt][r] = l_run[mt][r] * alpha + rs;
        for (int nt = 0; nt < 4; ++nt) oacc[mt][nt][r] *= alpha;
      }
    }

    // ---- O^T += P * V^T : C[m=lq][n=d] ----
    for (int kk = 0; kk < 2; ++kk) {
      bf16x8 ap[2];
      for (int mt = 0; mt < 2; ++mt)
        ap[mt] = *(const bf16x8*)&sm.a.Ps[wbase + mt * 16 + c][kk * 32 + qu * 8];
      for (int nt = 0; nt < 4; ++nt) {
        bf16x8 bv = *(const bf16x8*)&sm.a.Vs[nt * 16 + c][kk * 32 + qu * 8];
        for (int mt = 0; mt < 2; ++mt)
          oacc[mt][nt] = __builtin_amdgcn_mfma_f32_16x16x32_bf16(ap[mt], bv, oacc[mt][nt], 0, 0, 0);
      }
    }
  }

  // ---- epilogue: normalize, transpose via LDS, coalesced store ----
  __syncthreads();  // all PV reads done before overwriting the union
  for (int mt = 0; mt < 2; ++mt)
    for (int r = 0; r < 4; ++r) {
      float inv = 1.0f / l_run[mt][r];
      const int lq = wbase + mt * 16 + qu * 4 + r;
      for (int nt = 0; nt < 4; ++nt)
        sm.Oe[lq][nt * 16 + c] = oacc[mt][nt][r] * inv;
    }
  __syncthreads();
  float* op = out + hoff + q0;
  for (int i = 0; i < 32; ++i) {
    int idx = tid + i * 256;   // 0..8191
    int d   = idx >> 7;        // 0..63
    int lq  = idx & 127;
    op[d * LL + lq] = sm.Oe[lq][d];  // consecutive lanes -> consecutive lq: coalesced
  }
}

extern "C" void kernel_launch(void* const* d_in, const int* in_sizes, int n_in,
                              void* d_out, int out_size, void* d_ws, size_t ws_size,
                              hipStream_t stream) {
  const float* q = (const float*)d_in[0];
  const float* k = (const float*)d_in[1];
  const float* v = (const float*)d_in[2];
  float* out = (float*)d_out;
  dim3 grid(LL / TQ, 32);  // 16 q-tiles x (B*H=32) heads
  attn_flash_bf16<<<grid, 256, 0, stream>>>(q, k, v, out);
}

// Round 2
// 165.200 us; speedup vs baseline: 1.3632x; 1.3632x over previous
//
#include <hip/hip_runtime.h>
#include <math.h>

#define DD 64
#define LL 2048
#define TQ 128
#define TK 64
#define NT 512
// fold 1/sqrt(64) and log2(e); leaky_relu commutes with positive scaling
#define SCALE_LOG2 (0.125f * 1.44269504088896340736f)

typedef __bf16 bf16_t;
typedef __bf16 bf16x8 __attribute__((ext_vector_type(8)));
typedef __bf16 bf16x4 __attribute__((ext_vector_type(4)));
typedef float f32x4 __attribute__((ext_vector_type(4)));

// rows padded to 72 elems = 144 B = 9*16B: b128-aligned rows, odd 16B-groups/row
union __align__(16) SMem {
  struct {
    bf16_t Qs[TQ][72];   // [lq][d]  transposed
    bf16_t Ks[TK][72];   // [lk][d]  transposed
    bf16_t Vs[DD][72];   // [d][lk]  natural
    bf16_t Ps[TQ][72];   // [lq][lk] P round-trip (rows wave-private)
  } a;
  float Oe[TQ][65];      // epilogue transpose buffer
};

__device__ __forceinline__ unsigned pack_bf16(float lo, float hi) {
  union { bf16_t b[2]; unsigned u; } p;
  p.b[0] = (bf16_t)lo; p.b[1] = (bf16_t)hi;
  return p.u;
}

__global__ __launch_bounds__(512, 4)
void attn_flash_bf16(const float* __restrict__ q, const float* __restrict__ k,
                     const float* __restrict__ v, float* __restrict__ out) {
  __shared__ SMem sm;
  const int tid  = threadIdx.x;
  const int w    = tid >> 6;     // wave 0..7, owns rows [w*16, w*16+16)
  const int lane = tid & 63;
  const int qu   = lane >> 4;
  const int c    = lane & 15;
  const int head = blockIdx.y;
  const int q0   = blockIdx.x * TQ;
  const size_t hoff = (size_t)head * DD * LL;
  const float* qp = q + hoff;
  const float* kp = k + hoff;
  const float* vp = v + hoff;

  // ---- stage Q transposed once, packing 2 consecutive d per b32 write ----
  for (int i = 0; i < 2; ++i) {
    int idx = tid + NT * i;            // 0..1023
    int d2  = idx >> 5;                // 0..31 -> d = 2*d2, 2*d2+1
    int c4  = (idx & 31) * 4;          // lq 0..124
    float4 qa = *(const float4*)(qp + (2 * d2) * LL + q0 + c4);
    float4 qb = *(const float4*)(qp + (2 * d2 + 1) * LL + q0 + c4);
    *(unsigned*)&sm.a.Qs[c4 + 0][2 * d2] = pack_bf16(qa.x, qb.x);
    *(unsigned*)&sm.a.Qs[c4 + 1][2 * d2] = pack_bf16(qa.y, qb.y);
    *(unsigned*)&sm.a.Qs[c4 + 2][2 * d2] = pack_bf16(qa.z, qb.z);
    *(unsigned*)&sm.a.Qs[c4 + 3][2 * d2] = pack_bf16(qa.w, qb.w);
  }
  __syncthreads();

  // hoist loop-invariant Q A-fragments (row = w*16 + c)
  bf16x8 aq[2];
  aq[0] = *(const bf16x8*)&sm.a.Qs[w * 16 + c][qu * 8];
  aq[1] = *(const bf16x8*)&sm.a.Qs[w * 16 + c][32 + qu * 8];

  f32x4 oacc[4];
  float rsum[4] = {0.f, 0.f, 0.f, 0.f};
  for (int nt = 0; nt < 4; ++nt)
    for (int j = 0; j < 4; ++j) oacc[nt][j] = 0.f;

  for (int t = 0; t < LL / TK; ++t) {
    const int lk0 = t * TK;
    __syncthreads();  // prior tile's Ks/Vs reads done before restage
    // ---- K transposed (pack-2d b32 writes), V natural ----
    {
      int d2 = tid >> 4;               // 0..31
      int c4 = (tid & 15) * 4;         // lk 0..60
      float4 ka = *(const float4*)(kp + (2 * d2) * LL + lk0 + c4);
      float4 kb = *(const float4*)(kp + (2 * d2 + 1) * LL + lk0 + c4);
      *(unsigned*)&sm.a.Ks[c4 + 0][2 * d2] = pack_bf16(ka.x, kb.x);
      *(unsigned*)&sm.a.Ks[c4 + 1][2 * d2] = pack_bf16(ka.y, kb.y);
      *(unsigned*)&sm.a.Ks[c4 + 2][2 * d2] = pack_bf16(ka.z, kb.z);
      *(unsigned*)&sm.a.Ks[c4 + 3][2 * d2] = pack_bf16(ka.w, kb.w);
    }
    for (int i = 0; i < 2; ++i) {
      int idx = tid + NT * i;          // 0..1023
      int d   = idx >> 4;              // 0..63
      int c4  = (idx & 15) * 4;
      float4 vv = *(const float4*)(vp + d * LL + lk0 + c4);
      bf16x4 pk;
      pk[0] = (bf16_t)vv.x; pk[1] = (bf16_t)vv.y;
      pk[2] = (bf16_t)vv.z; pk[3] = (bf16_t)vv.w;
      *(bf16x4*)&sm.a.Vs[d][c4] = pk;
    }
    __syncthreads();

    // ---- S = Q^T K : per-wave 16x64 strip ----
    f32x4 sacc[4];
    for (int nt = 0; nt < 4; ++nt)
      for (int j = 0; j < 4; ++j) sacc[nt][j] = 0.f;
    for (int kk = 0; kk < 2; ++kk)
      for (int nt = 0; nt < 4; ++nt) {
        bf16x8 bk = *(const bf16x8*)&sm.a.Ks[nt * 16 + c][kk * 32 + qu * 8];
        sacc[nt] = __builtin_amdgcn_mfma_f32_16x16x32_bf16(aq[kk], bk, sacc[nt], 0, 0, 0);
      }

    // ---- softmax numerator only (fixed max = 0), deferred row-sum ----
    for (int r = 0; r < 4; ++r) {
      const int lq = w * 16 + qu * 4 + r;
      for (int nt = 0; nt < 4; ++nt) {
        float s = sacc[nt][r] * SCALE_LOG2;
        s = fmaxf(s, 0.01f * s);                 // leaky_relu in log2 domain
        float p = __builtin_amdgcn_exp2f(s);
        rsum[r] += p;
        sm.a.Ps[lq][nt * 16 + c] = (bf16_t)p;    // wave-private rows
      }
    }

    // ---- O^T += P V^T ----
    for (int kk = 0; kk < 2; ++kk) {
      bf16x8 ap = *(const bf16x8*)&sm.a.Ps[w * 16 + c][kk * 32 + qu * 8];
      for (int nt = 0; nt < 4; ++nt) {
        bf16x8 bv = *(const bf16x8*)&sm.a.Vs[nt * 16 + c][kk * 32 + qu * 8];
        oacc[nt] = __builtin_amdgcn_mfma_f32_16x16x32_bf16(ap, bv, oacc[nt], 0, 0, 0);
      }
    }
  }

  // ---- one-time row-sum reduction over the 16 c-lanes ----
  for (int r = 0; r < 4; ++r) {
    float rs = rsum[r];
    rs += __shfl_xor(rs, 1);
    rs += __shfl_xor(rs, 2);
    rs += __shfl_xor(rs, 4);
    rs += __shfl_xor(rs, 8);
    rsum[r] = 1.0f / rs;
  }

  // ---- epilogue: normalize, transpose via LDS, coalesced store ----
  __syncthreads();  // all PV reads done before overwriting the union
  for (int r = 0; r < 4; ++r) {
    const int lq = w * 16 + qu * 4 + r;
    for (int nt = 0; nt < 4; ++nt)
      sm.Oe[lq][nt * 16 + c] = oacc[nt][r] * rsum[r];
  }
  __syncthreads();
  float* op = out + hoff + q0;
  for (int i = 0; i < 16; ++i) {
    int idx = tid + NT * i;   // 0..8191
    int d   = idx >> 7;       // 0..63
    int lq  = idx & 127;
    op[d * LL + lq] = sm.Oe[lq][d];
  }
}

extern "C" void kernel_launch(void* const* d_in, const int* in_sizes, int n_in,
                              void* d_out, int out_size, void* d_ws, size_t ws_size,
                              hipStream_t stream) {
  const float* q = (const float*)d_in[0];
  const float* k = (const float*)d_in[1];
  const float* v = (const float*)d_in[2];
  float* out = (float*)d_out;
  dim3 grid(LL / TQ, 32);  // 16 q-tiles x (B*H=32)
  attn_flash_bf16<<<grid, 512, 0, stream>>>(q, k, v, out);
}